// Round 12
// baseline (473.577 us; speedup 1.0000x reference)
//
#include <hip/hip_runtime.h>
#include <hip/hip_bf16.h>

using bf16 = __hip_bfloat16;
using v8s = __attribute__((ext_vector_type(8))) short;   // MFMA A/B frag: 8 bf16
using v4f = __attribute__((ext_vector_type(4))) float;   // MFMA C/D frag

// Problem constants (from reference)
constexpr int kB = 4, kM = 64;
constexpr int kN2 = 512, kN1 = 2048, kN0 = 8192;
constexpr int kC2 = 256, kC1 = 128, kC0 = 64;

__device__ __forceinline__ float bf2f(bf16 v) { return __bfloat162float(v); }
__device__ __forceinline__ float bs2f(unsigned short u) {
    unsigned w = (unsigned)u << 16;
    return __uint_as_float(w);
}
__device__ __forceinline__ unsigned short f2bs(float f) {  // RNE fp32->bf16
    unsigned u = __float_as_uint(f);
    u += 0x7FFFu + ((u >> 16) & 1u);
    return (unsigned short)(u >> 16);
}
__device__ __forceinline__ float rdIn(const void* p, long i, int f32) {
    return f32 ? ((const float*)p)[i] : bs2f(((const unsigned short*)p)[i]);
}
__device__ __forceinline__ unsigned short rdBS(const void* p, long i, int f32) {
    return f32 ? f2bs(((const float*)p)[i]) : ((const unsigned short*)p)[i];
}

// ===========================================================================
// dtype probe on `pos` (uniform [0,1)). flag: 1 = fp32, 0 = bf16.
// ===========================================================================
__global__ void fpno_probe_dtype(const unsigned int* __restrict__ w,
                                 int* __restrict__ flag) {
    __shared__ int sBad, sNz;
    if (threadIdx.x == 0) { sBad = 0; sNz = 0; }
    __syncthreads();
    int bad = 0, nz = 0;
    for (int j = 0; j < 2; j++) {
        unsigned lo = w[threadIdx.x + 256 * j] & 0xFFFFu;  // words 0..511 < 3072
        if (lo != 0u) { nz = 1; if ((lo & 0x8000u) || lo > 0x3F80u) bad = 1; }
    }
    if (bad) sBad = 1;
    if (nz) sNz = 1;
    __syncthreads();
    if (threadIdx.x == 0) *flag = (sBad || !sNz) ? 1 : 0;
}

// ===========================================================================
// per-sample gate vectors: g0[b][n] = tanh(par[b] @ Wp0 + bp0)[n]; g1 likewise
// ===========================================================================
__global__ void fpno_gates(const void* __restrict__ par,
                           const void* __restrict__ Wp0, const void* __restrict__ bp0,
                           const void* __restrict__ Wp1, const void* __restrict__ bp1,
                           const int* __restrict__ flagp,
                           float* __restrict__ g0, float* __restrict__ g1) {
    const int f32 = *flagp;
    int id = blockIdx.x * 256 + threadIdx.x;
    if (id < kB * 128) {
        int b = id / 128, n = id % 128;
        float a = rdIn(bp0, n, f32);
        for (int m = 0; m < kM; m++)
            a += rdIn(par, b * kM + m, f32) * rdIn(Wp0, m * 128 + n, f32);
        g0[id] = tanhf(a);
    } else if (id < kB * 128 + kB * 64) {
        int id2 = id - kB * 128;
        int b = id2 / 64, n = id2 % 64;
        float a = rdIn(bp1, n, f32);
        for (int m = 0; m < kM; m++)
            a += rdIn(par, b * kM + m, f32) * rdIn(Wp1, m * 64 + n, f32);
        g1[id2] = tanhf(a);
    }
}

// ===========================================================================
// kNN k=3, split-scan (round-11 version, proven): 32 targets x 8 splits/block.
// Selection bit-identical to serial scan (contract off, strict '<', (d,idx)
// tie-break at merge).
// ===========================================================================
template <int NS>
__global__ void fpno_nn3s(const void* __restrict__ srcP, const void* __restrict__ tgtP,
                          const int* __restrict__ flagp, int tgtPerSample,
                          int* __restrict__ oIdx, float* __restrict__ oW) {
    #pragma clang fp contract(off)
    constexpr int SPLIT = 8;
    constexpr int TPB = 256 / SPLIT;
    __shared__ float4 sp[NS];
    __shared__ float cd[256 * 3];
    __shared__ int   ci[256 * 3];
    const int f32 = *flagp;
    const int tid = threadIdx.x;
    const int tLoc = tid >> 3;
    const int spl  = tid & 7;
    const int tGlob = blockIdx.x * TPB + tLoc;
    const int smp = tGlob / tgtPerSample;
    for (int i = tid; i < NS; i += 256) {
        long b = (long)(smp * NS + i) * 3;
        sp[i] = make_float4(rdIn(srcP, b, f32), rdIn(srcP, b + 1, f32),
                            rdIn(srcP, b + 2, f32), 0.f);
    }
    __syncthreads();
    long tb = (long)tGlob * 3;
    float px = rdIn(tgtP, tb, f32), py = rdIn(tgtP, tb + 1, f32),
          pz = rdIn(tgtP, tb + 2, f32);
    float d0 = 1e30f, d1 = 1e30f, d2 = 1e30f;
    int i0 = 0x7FFFFFFF, i1 = 0x7FFFFFFF, i2 = 0x7FFFFFFF;
    for (int j = spl; j < NS; j += SPLIT) {
        float4 s = sp[j];
        float dx = px - s.x, dy = py - s.y, dz = pz - s.z;
        float d = ((dx * dx) + (dy * dy)) + (dz * dz);
        bool l0 = d < d0, l1 = d < d1, l2 = d < d2;
        float nd2 = l1 ? d1 : (l2 ? d : d2);
        int   ni2 = l1 ? i1 : (l2 ? j : i2);
        float nd1 = l0 ? d0 : (l1 ? d : d1);
        int   ni1 = l0 ? i0 : (l1 ? j : i1);
        float nd0 = l0 ? d : d0;
        int   ni0 = l0 ? j : i0;
        d2 = nd2; i2 = ni2; d1 = nd1; i1 = ni1; d0 = nd0; i0 = ni0;
    }
    cd[tid * 3 + 0] = d0; ci[tid * 3 + 0] = i0;
    cd[tid * 3 + 1] = d1; ci[tid * 3 + 1] = i1;
    cd[tid * 3 + 2] = d2; ci[tid * 3 + 2] = i2;
    __syncthreads();
    if (spl == 0) {
        float b0 = 1e30f, b1 = 1e30f, b2 = 1e30f;
        int k0 = 0x7FFFFFFF, k1 = 0x7FFFFFFF, k2 = 0x7FFFFFFF;
        int qb = tLoc * SPLIT * 3;
        for (int q = 0; q < SPLIT * 3; q++) {
            float d = cd[qb + q];
            int i = ci[qb + q];
            if ((d < b2) || (d == b2 && i < k2)) {
                if ((d < b1) || (d == b1 && i < k1)) {
                    b2 = b1; k2 = k1;
                    if ((d < b0) || (d == b0 && i < k0)) { b1 = b0; k1 = k0; b0 = d; k0 = i; }
                    else                                  { b1 = d;  k1 = i; }
                } else { b2 = d; k2 = i; }
            }
        }
        float wa = 1.f / fmaxf(b0, 1e-16f);
        float wb = 1.f / fmaxf(b1, 1e-16f);
        float wc = 1.f / fmaxf(b2, 1e-16f);
        float s = wa + wb + wc;
        oIdx[tGlob * 3 + 0] = smp * NS + k0;
        oIdx[tGlob * 3 + 1] = smp * NS + k1;
        oIdx[tGlob * 3 + 2] = smp * NS + k2;
        oW[tGlob * 3 + 0] = wa / s;
        oW[tGlob * 3 + 1] = wb / s;
        oW[tGlob * 3 + 2] = wc / s;
    }
}

// ===========================================================================
// MFMA stage-A: H[M,Nd] = tanh(Xcat @ W + b), bf16 MFMA 16x16x32, fp32 acc.
// Xcat built on the fly (col<CF: 3-gather interp; col>=CF: skip features).
// Block = 4 waves, tile 64x64; wave computes 16 rows x 4 n-tiles.
// A staged in LDS bf16, row pad 40 halves (<=2-way bank aliasing = free).
// A-frag: lane holds A[m=lane&15][k=quad*8+j] -> one ds_read_b128.
// B-frag: global fragment-layout loads (weights are small, cache-resident).
// C/D: col=lane&15, row=quad*4+reg (verified layout).
// H output: bf16 workspace.
// ===========================================================================
template <int CF, int CS>
__global__ void fpno_mf_a(const void* __restrict__ feats_raw,
                          const unsigned short* __restrict__ featsBF,
                          const void* __restrict__ skip_raw,
                          const void* __restrict__ W, const void* __restrict__ bv,
                          const int* __restrict__ idx, const float* __restrict__ wgt,
                          const int* __restrict__ flagp,
                          unsigned short* __restrict__ H, int Nd) {
    constexpr int KD = CF + CS;
    __shared__ unsigned short As[64 * 40];
    const int f32 = *flagp;
    const int tid = threadIdx.x;
    const int lane = tid & 63, wv = tid >> 6;
    const int l16 = lane & 15, quad = lane >> 4;
    const int bm = blockIdx.x, bn = blockIdx.y;
    const int row = tid >> 2;       // staging row 0..63
    const int seg = tid & 3;        // 8-k segment within 32-k chunk
    const int rg = bm * 64 + row;

    int j0 = idx[rg * 3 + 0], j1 = idx[rg * 3 + 1], j2 = idx[rg * 3 + 2];
    float w0 = wgt[rg * 3 + 0], w1 = wgt[rg * 3 + 1], w2 = wgt[rg * 3 + 2];

    v4f acc[4];
    #pragma unroll
    for (int t = 0; t < 4; t++) acc[t] = (v4f){0.f, 0.f, 0.f, 0.f};

    for (int k0 = 0; k0 < KD; k0 += 32) {
        // build this thread's 8 Xcat elements (chunks are purely one side:
        // CF is a multiple of 32)
        v8s vv;
        int kb = k0 + seg * 8;
        if (kb < CF) {
            #pragma unroll
            for (int j = 0; j < 8; j++) {
                int kk = kb + j;
                float v;
                if (featsBF) {
                    v = w0 * bs2f(featsBF[(long)j0 * CF + kk])
                      + w1 * bs2f(featsBF[(long)j1 * CF + kk])
                      + w2 * bs2f(featsBF[(long)j2 * CF + kk]);
                } else {
                    v = w0 * rdIn(feats_raw, (long)j0 * CF + kk, f32)
                      + w1 * rdIn(feats_raw, (long)j1 * CF + kk, f32)
                      + w2 * rdIn(feats_raw, (long)j2 * CF + kk, f32);
                }
                vv[j] = (short)f2bs(v);
            }
        } else {
            #pragma unroll
            for (int j = 0; j < 8; j++)
                vv[j] = (short)rdBS(skip_raw, (long)rg * CS + (kb - CF) + j, f32);
        }
        __syncthreads();
        *(v8s*)&As[row * 40 + seg * 8] = vv;
        __syncthreads();

        const v8s a = *(const v8s*)&As[(wv * 16 + l16) * 40 + quad * 8];
        long kg = (long)(k0 + quad * 8);
        #pragma unroll
        for (int t = 0; t < 4; t++) {
            int colg = bn * 64 + t * 16 + l16;
            v8s b;
            #pragma unroll
            for (int j = 0; j < 8; j++)
                b[j] = (short)rdBS(W, (kg + j) * Nd + colg, f32);
            acc[t] = __builtin_amdgcn_mfma_f32_16x16x32_bf16(a, b, acc[t], 0, 0, 0);
        }
    }

    #pragma unroll
    for (int t = 0; t < 4; t++) {
        int c = bn * 64 + t * 16 + l16;
        float bb = rdIn(bv, c, f32);
        #pragma unroll
        for (int i = 0; i < 4; i++) {
            int r = bm * 64 + wv * 16 + quad * 4 + i;
            H[(long)r * Nd + c] = f2bs(tanhf(acc[t][i] + bb));
        }
    }
}

// ===========================================================================
// MFMA stage-B: Y = act(H @ W + b) * gate. H = bf16 ws. Same MFMA core.
// OUTBF: bf16 ws output (X1) vs fp32 final output (d_out is fp32!).
// ===========================================================================
template <bool TANH, bool OUTBF, int SMPSHIFT>
__global__ void fpno_mf_b(const unsigned short* __restrict__ Hs,
                          const void* __restrict__ W, const void* __restrict__ bv,
                          const float* __restrict__ gate, const int* __restrict__ flagp,
                          void* __restrict__ Y, int Kd, int Nd) {
    __shared__ unsigned short As[64 * 40];
    const int f32 = *flagp;
    const int tid = threadIdx.x;
    const int lane = tid & 63, wv = tid >> 6;
    const int l16 = lane & 15, quad = lane >> 4;
    const int bm = blockIdx.x, bn = blockIdx.y;
    const int row = tid >> 2, seg = tid & 3;

    v4f acc[4];
    #pragma unroll
    for (int t = 0; t < 4; t++) acc[t] = (v4f){0.f, 0.f, 0.f, 0.f};

    for (int k0 = 0; k0 < Kd; k0 += 32) {
        uint4 hv = *(const uint4*)&Hs[(long)(bm * 64 + row) * Kd + k0 + seg * 8];
        __syncthreads();
        *(uint4*)&As[row * 40 + seg * 8] = hv;
        __syncthreads();

        const v8s a = *(const v8s*)&As[(wv * 16 + l16) * 40 + quad * 8];
        long kg = (long)(k0 + quad * 8);
        #pragma unroll
        for (int t = 0; t < 4; t++) {
            int colg = bn * 64 + t * 16 + l16;
            v8s b;
            #pragma unroll
            for (int j = 0; j < 8; j++)
                b[j] = (short)rdBS(W, (kg + j) * Nd + colg, f32);
            acc[t] = __builtin_amdgcn_mfma_f32_16x16x32_bf16(a, b, acc[t], 0, 0, 0);
        }
    }

    #pragma unroll
    for (int t = 0; t < 4; t++) {
        int c = bn * 64 + t * 16 + l16;
        float bb = rdIn(bv, c, f32);
        #pragma unroll
        for (int i = 0; i < 4; i++) {
            int r = bm * 64 + wv * 16 + quad * 4 + i;
            float v = acc[t][i] + bb;
            if (TANH) v = tanhf(v);
            v *= gate[(r >> SMPSHIFT) * Nd + c];
            if (OUTBF) ((unsigned short*)Y)[(long)r * Nd + c] = f2bs(v);
            else       ((float*)Y)[(long)r * Nd + c] = v;
        }
    }
}

// ===========================================================================
// output tail (fp32): [pos_skip_l0 (32768*3) | batch_skip_l0 (32768)]
// ===========================================================================
__global__ void fpno_tail(const void* __restrict__ pos0, const int* __restrict__ bt0,
                          const int* __restrict__ flagp, float* __restrict__ out) {
    const int f32 = *flagp;
    int id = blockIdx.x * 256 + threadIdx.x;  // 0..131071
    const int nX = kB * kN0 * kC0;   // 2097152
    const int nP = kB * kN0 * 3;     // 98304
    if (id < nP) out[nX + id] = rdIn(pos0, id, f32);
    else         out[nX + id] = (float)bt0[id - nP];
}

__global__ void fpno_guard(float code, float* __restrict__ out) {
    if (threadIdx.x == 0) out[0] = code;
}

// ===========================================================================
extern "C" void kernel_launch(void* const* d_in, const int* in_sizes, int n_in,
                              void* d_out, int out_size, void* d_ws, size_t ws_size,
                              hipStream_t stream) {
    (void)out_size;
    float* out = (float*)d_out;   // fp32 output buffer
    const int R1 = kB * kN1;  // 8192
    const int R0 = kB * kN0;  // 32768

    static const int kExp[22] = {
        256, 524288, 6144, 2048, 1048576, 24576, 8192, 2097152, 98304, 32768,
        98304, 256, 32768, 128, 8192, 128, 24576, 128, 8192, 64, 4096, 64};
    if (n_in != 22) { fpno_guard<<<1, 64, 0, stream>>>(3072.0f, out); return; }
    for (int i = 0; i < 22; i++) {
        if (in_sizes[i] != kExp[i]) {
            fpno_guard<<<1, 64, 0, stream>>>(1024.0f + 8.0f * i, out);
            return;
        }
    }

    // ---- workspace (~14 MB: H1/X1/H2 now bf16) ----
    char* base = (char*)d_ws;
    size_t off = 0;
    auto alloc = [&](size_t bytes) {
        off = (off + 255) & ~(size_t)255; size_t o = off; off += bytes; return o;
    };
    int*            flag = (int*)(base + alloc(4));
    float*          g0   = (float*)(base + alloc(kB * 128 * 4));
    float*          g1   = (float*)(base + alloc(kB * 64 * 4));
    int*            i1d  = (int*)(base + alloc((size_t)R1 * 3 * 4));
    float*          w1d  = (float*)(base + alloc((size_t)R1 * 3 * 4));
    int*            i0d  = (int*)(base + alloc((size_t)R0 * 3 * 4));
    float*          w0d  = (float*)(base + alloc((size_t)R0 * 3 * 4));
    unsigned short* H1   = (unsigned short*)(base + alloc((size_t)R1 * 256 * 2));  // 4 MB
    unsigned short* X1   = (unsigned short*)(base + alloc((size_t)R1 * 128 * 2));  // 2 MB
    unsigned short* H2   = (unsigned short*)(base + alloc((size_t)R0 * 128 * 2));  // 8 MB
    if (ws_size < off) { fpno_guard<<<1, 64, 0, stream>>>(2048.0f, out); return; }

    const void* par  = d_in[0];
    const void* x    = d_in[1];
    const void* pos  = d_in[2];
    const void* xs1  = d_in[4];
    const void* pos1 = d_in[5];
    const void* xs0  = d_in[7];
    const void* pos0 = d_in[8];
    const int*  bt0  = (const int*)d_in[9];
    const void *W0a = d_in[10], *b0a = d_in[11], *W0b = d_in[12], *b0b = d_in[13];
    const void *Wp0 = d_in[14], *bp0 = d_in[15];
    const void *W1a = d_in[16], *b1a = d_in[17], *W1b = d_in[18], *b1b = d_in[19];
    const void *Wp1 = d_in[20], *bp1 = d_in[21];

    // 1) input dtype probe
    fpno_probe_dtype<<<1, 256, 0, stream>>>((const unsigned int*)pos, flag);

    // 2) per-sample gates
    fpno_gates<<<3, 256, 0, stream>>>(par, Wp0, bp0, Wp1, bp1, flag, g0, g1);

    // 3) layer-1 kNN
    fpno_nn3s<kN2><<<R1 / 32, 256, 0, stream>>>(pos, pos1, flag, kN1, i1d, w1d);

    // 4) H1 = tanh([interp(x), xs1] @ W0a + b0a)    8192x384 @ 384x256  (MFMA)
    fpno_mf_a<kC2, kC1><<<dim3(R1 / 64, 4), 256, 0, stream>>>(
        x, nullptr, xs1, W0a, b0a, i1d, w1d, flag, H1, 256);

    // 5) X1 = tanh(H1 @ W0b + b0b) * g0             8192x256 @ 256x128  (MFMA)
    fpno_mf_b<true, true, 11><<<dim3(R1 / 64, 2), 256, 0, stream>>>(
        H1, W0b, b0b, g0, flag, X1, 256, 128);

    // 6) layer-2 kNN
    fpno_nn3s<kN1><<<R0 / 32, 256, 0, stream>>>(pos1, pos0, flag, kN0, i0d, w0d);

    // 7) H2 = tanh([interp(X1), xs0] @ W1a + b1a)   32768x192 @ 192x128 (MFMA)
    fpno_mf_a<kC1, kC0><<<dim3(R0 / 64, 2), 256, 0, stream>>>(
        nullptr, X1, xs0, W1a, b1a, i0d, w0d, flag, H2, 128);

    // 8) x0 = (H2 @ W1b + b1b) * g1 -> fp32 out     32768x128 @ 128x64  (MFMA)
    fpno_mf_b<false, false, 13><<<dim3(R0 / 64, 1), 256, 0, stream>>>(
        H2, W1b, b1b, g1, flag, out, 128, 64);

    // 9) tail passthrough (fp32)
    fpno_tail<<<(kB * kN0 * 4) / 256, 256, 0, stream>>>(pos0, bt0, flag, out);
}

// Round 13
// 245.619 us; speedup vs baseline: 1.9281x; 1.9281x over previous
//
#include <hip/hip_runtime.h>
#include <hip/hip_bf16.h>

using bf16 = __hip_bfloat16;
using v8s = __attribute__((ext_vector_type(8))) short;   // MFMA A/B frag: 8 bf16
using v4f = __attribute__((ext_vector_type(4))) float;   // MFMA C/D frag

// Problem constants (from reference)
constexpr int kB = 4, kM = 64;
constexpr int kN2 = 512, kN1 = 2048, kN0 = 8192;
constexpr int kC2 = 256, kC1 = 128, kC0 = 64;

__device__ __forceinline__ float bs2f(unsigned short u) {
    return __uint_as_float((unsigned)u << 16);
}
__device__ __forceinline__ unsigned short f2bs(float f) {  // RNE fp32->bf16
    unsigned u = __float_as_uint(f);
    u += 0x7FFFu + ((u >> 16) & 1u);
    return (unsigned short)(u >> 16);
}
__device__ __forceinline__ float rdIn(const void* p, long i, int f32) {
    return f32 ? ((const float*)p)[i] : bs2f(((const unsigned short*)p)[i]);
}
__device__ __forceinline__ unsigned short rdBS(const void* p, long i, int f32) {
    return f32 ? f2bs(((const float*)p)[i]) : ((const unsigned short*)p)[i];
}
// load 8 consecutive elements as fp32 (16B-aligned offsets only)
__device__ __forceinline__ void ld8(const void* p, long off, int f32, float v[8]) {
    if (f32) {
        const float* fp = (const float*)p + off;
        float4 a = *(const float4*)fp;
        float4 b = *(const float4*)(fp + 4);
        v[0] = a.x; v[1] = a.y; v[2] = a.z; v[3] = a.w;
        v[4] = b.x; v[5] = b.y; v[6] = b.z; v[7] = b.w;
    } else {
        const unsigned short* hp = (const unsigned short*)p + off;
        uint4 u = *(const uint4*)hp;
        unsigned w[4] = {u.x, u.y, u.z, u.w};
        #pragma unroll
        for (int i = 0; i < 4; i++) {
            v[2 * i]     = bs2f((unsigned short)(w[i] & 0xFFFFu));
            v[2 * i + 1] = bs2f((unsigned short)(w[i] >> 16));
        }
    }
}

// ===========================================================================
// dtype probe on `pos` (uniform [0,1)). flag: 1 = fp32, 0 = bf16.
// ===========================================================================
__global__ void fpno_probe_dtype(const unsigned int* __restrict__ w,
                                 int* __restrict__ flag) {
    __shared__ int sBad, sNz;
    if (threadIdx.x == 0) { sBad = 0; sNz = 0; }
    __syncthreads();
    int bad = 0, nz = 0;
    for (int j = 0; j < 2; j++) {
        unsigned lo = w[threadIdx.x + 256 * j] & 0xFFFFu;  // words 0..511 < 3072
        if (lo != 0u) { nz = 1; if ((lo & 0x8000u) || lo > 0x3F80u) bad = 1; }
    }
    if (bad) sBad = 1;
    if (nz) sNz = 1;
    __syncthreads();
    if (threadIdx.x == 0) *flag = (sBad || !sNz) ? 1 : 0;
}

// ===========================================================================
// one-time weight convert+transpose to bf16: WT[n][k] = W[k][n].
// All 4 weight matrices packed into one 163840-half region (L2-resident).
// Round-12 lesson: per-MFMA scalar 2-byte W loads left both pipes idle
// (MfmaUtil 0.4%); with WT a B-fragment is ONE global_load_dwordx4.
// ===========================================================================
__global__ void fpno_wconv(const void* __restrict__ W0a, const void* __restrict__ W0b,
                           const void* __restrict__ W1a, const void* __restrict__ W1b,
                           const int* __restrict__ flagp, unsigned short* __restrict__ WT) {
    const int f32 = *flagp;
    int tid = blockIdx.x * 256 + threadIdx.x;
    const void* src; int N, K; int base, local;
    if      (tid < 98304)  { src = W0a; N = 256; K = 384; base = 0;      local = tid; }
    else if (tid < 131072) { src = W0b; N = 128; K = 256; base = 98304;  local = tid - 98304; }
    else if (tid < 155648) { src = W1a; N = 128; K = 192; base = 131072; local = tid - 131072; }
    else if (tid < 163840) { src = W1b; N = 64;  K = 128; base = 155648; local = tid - 155648; }
    else return;
    int n = local / K, k = local % K;
    WT[base + local] = rdBS(src, (long)k * N + n, f32);
}

// ===========================================================================
// per-sample gate vectors: g0[b][n] = tanh(par[b] @ Wp0 + bp0)[n]; g1 likewise
// ===========================================================================
__global__ void fpno_gates(const void* __restrict__ par,
                           const void* __restrict__ Wp0, const void* __restrict__ bp0,
                           const void* __restrict__ Wp1, const void* __restrict__ bp1,
                           const int* __restrict__ flagp,
                           float* __restrict__ g0, float* __restrict__ g1) {
    const int f32 = *flagp;
    int id = blockIdx.x * 256 + threadIdx.x;
    if (id < kB * 128) {
        int b = id / 128, n = id % 128;
        float a = rdIn(bp0, n, f32);
        for (int m = 0; m < kM; m++)
            a += rdIn(par, b * kM + m, f32) * rdIn(Wp0, m * 128 + n, f32);
        g0[id] = tanhf(a);
    } else if (id < kB * 128 + kB * 64) {
        int id2 = id - kB * 128;
        int b = id2 / 64, n = id2 % 64;
        float a = rdIn(bp1, n, f32);
        for (int m = 0; m < kM; m++)
            a += rdIn(par, b * kM + m, f32) * rdIn(Wp1, m * 64 + n, f32);
        g1[id2] = tanhf(a);
    }
}

// ===========================================================================
// kNN k=3, split-scan (proven): 32 targets x 8 splits/block. Selection
// bit-identical to serial scan (contract off, strict '<', (d,idx) tie-break).
// ===========================================================================
template <int NS>
__global__ void fpno_nn3s(const void* __restrict__ srcP, const void* __restrict__ tgtP,
                          const int* __restrict__ flagp, int tgtPerSample,
                          int* __restrict__ oIdx, float* __restrict__ oW) {
    #pragma clang fp contract(off)
    constexpr int SPLIT = 8;
    constexpr int TPB = 256 / SPLIT;
    __shared__ float4 sp[NS];
    __shared__ float cd[256 * 3];
    __shared__ int   ci[256 * 3];
    const int f32 = *flagp;
    const int tid = threadIdx.x;
    const int tLoc = tid >> 3;
    const int spl  = tid & 7;
    const int tGlob = blockIdx.x * TPB + tLoc;
    const int smp = tGlob / tgtPerSample;
    for (int i = tid; i < NS; i += 256) {
        long b = (long)(smp * NS + i) * 3;
        sp[i] = make_float4(rdIn(srcP, b, f32), rdIn(srcP, b + 1, f32),
                            rdIn(srcP, b + 2, f32), 0.f);
    }
    __syncthreads();
    long tb = (long)tGlob * 3;
    float px = rdIn(tgtP, tb, f32), py = rdIn(tgtP, tb + 1, f32),
          pz = rdIn(tgtP, tb + 2, f32);
    float d0 = 1e30f, d1 = 1e30f, d2 = 1e30f;
    int i0 = 0x7FFFFFFF, i1 = 0x7FFFFFFF, i2 = 0x7FFFFFFF;
    for (int j = spl; j < NS; j += SPLIT) {
        float4 s = sp[j];
        float dx = px - s.x, dy = py - s.y, dz = pz - s.z;
        float d = ((dx * dx) + (dy * dy)) + (dz * dz);
        bool l0 = d < d0, l1 = d < d1, l2 = d < d2;
        float nd2 = l1 ? d1 : (l2 ? d : d2);
        int   ni2 = l1 ? i1 : (l2 ? j : i2);
        float nd1 = l0 ? d0 : (l1 ? d : d1);
        int   ni1 = l0 ? i0 : (l1 ? j : i1);
        float nd0 = l0 ? d : d0;
        int   ni0 = l0 ? j : i0;
        d2 = nd2; i2 = ni2; d1 = nd1; i1 = ni1; d0 = nd0; i0 = ni0;
    }
    cd[tid * 3 + 0] = d0; ci[tid * 3 + 0] = i0;
    cd[tid * 3 + 1] = d1; ci[tid * 3 + 1] = i1;
    cd[tid * 3 + 2] = d2; ci[tid * 3 + 2] = i2;
    __syncthreads();
    if (spl == 0) {
        float b0 = 1e30f, b1 = 1e30f, b2 = 1e30f;
        int k0 = 0x7FFFFFFF, k1 = 0x7FFFFFFF, k2 = 0x7FFFFFFF;
        int qb = tLoc * SPLIT * 3;
        for (int q = 0; q < SPLIT * 3; q++) {
            float d = cd[qb + q];
            int i = ci[qb + q];
            if ((d < b2) || (d == b2 && i < k2)) {
                if ((d < b1) || (d == b1 && i < k1)) {
                    b2 = b1; k2 = k1;
                    if ((d < b0) || (d == b0 && i < k0)) { b1 = b0; k1 = k0; b0 = d; k0 = i; }
                    else                                  { b1 = d;  k1 = i; }
                } else { b2 = d; k2 = i; }
            }
        }
        float wa = 1.f / fmaxf(b0, 1e-16f);
        float wb = 1.f / fmaxf(b1, 1e-16f);
        float wc = 1.f / fmaxf(b2, 1e-16f);
        float s = wa + wb + wc;
        oIdx[tGlob * 3 + 0] = smp * NS + k0;
        oIdx[tGlob * 3 + 1] = smp * NS + k1;
        oIdx[tGlob * 3 + 2] = smp * NS + k2;
        oW[tGlob * 3 + 0] = wa / s;
        oW[tGlob * 3 + 1] = wb / s;
        oW[tGlob * 3 + 2] = wc / s;
    }
}

// ===========================================================================
// MFMA stage-A: H[M,Nd] = tanh(Xcat @ W + b), bf16 MFMA 16x16x32, fp32 acc.
// Xcat on the fly: col<CF interp 3-gather (WIDE 8-elem loads), col>=CF skip.
// B-frag: one uint4 from transposed bf16 WT[n][k] (L2-resident).
// A staged in LDS bf16, row pad 40 halves. C/D: col=lane&15, row=quad*4+reg.
// ===========================================================================
template <int CF, int CS>
__global__ void fpno_mf_a(const void* __restrict__ feats_raw,
                          const unsigned short* __restrict__ featsBF,
                          const void* __restrict__ skip_raw,
                          const unsigned short* __restrict__ WT,
                          const void* __restrict__ bv,
                          const int* __restrict__ idx, const float* __restrict__ wgt,
                          const int* __restrict__ flagp,
                          unsigned short* __restrict__ H, int Nd) {
    constexpr int KD = CF + CS;
    __shared__ unsigned short As[64 * 40];
    const int f32 = *flagp;
    const int tid = threadIdx.x;
    const int lane = tid & 63, wv = tid >> 6;
    const int l16 = lane & 15, quad = lane >> 4;
    const int bm = blockIdx.x, bn = blockIdx.y;
    const int row = tid >> 2;       // staging row 0..63
    const int seg = tid & 3;        // 8-k segment within 32-k chunk
    const int rg = bm * 64 + row;

    int j0 = idx[rg * 3 + 0], j1 = idx[rg * 3 + 1], j2 = idx[rg * 3 + 2];
    float w0 = wgt[rg * 3 + 0], w1 = wgt[rg * 3 + 1], w2 = wgt[rg * 3 + 2];
    const void* fsrc = featsBF ? (const void*)featsBF : feats_raw;
    const int ff32 = featsBF ? 0 : f32;

    v4f acc[4];
    #pragma unroll
    for (int t = 0; t < 4; t++) acc[t] = (v4f){0.f, 0.f, 0.f, 0.f};

    for (int k0 = 0; k0 < KD; k0 += 32) {
        v8s vv;
        int kb = k0 + seg * 8;
        if (kb < CF) {   // CF % 32 == 0: chunk is purely one side
            float a0[8], a1[8], a2[8];
            ld8(fsrc, (long)j0 * CF + kb, ff32, a0);
            ld8(fsrc, (long)j1 * CF + kb, ff32, a1);
            ld8(fsrc, (long)j2 * CF + kb, ff32, a2);
            #pragma unroll
            for (int j = 0; j < 8; j++)
                vv[j] = (short)f2bs(w0 * a0[j] + w1 * a1[j] + w2 * a2[j]);
        } else {
            float s8[8];
            ld8(skip_raw, (long)rg * CS + (kb - CF), f32, s8);
            #pragma unroll
            for (int j = 0; j < 8; j++) vv[j] = (short)f2bs(s8[j]);
        }
        __syncthreads();
        *(v8s*)&As[row * 40 + seg * 8] = vv;
        __syncthreads();

        const v8s a = *(const v8s*)&As[(wv * 16 + l16) * 40 + quad * 8];
        long kg = (long)(k0 + quad * 8);
        #pragma unroll
        for (int t = 0; t < 4; t++) {
            int colg = bn * 64 + t * 16 + l16;
            const v8s b = *(const v8s*)&WT[(long)colg * KD + kg];
            acc[t] = __builtin_amdgcn_mfma_f32_16x16x32_bf16(a, b, acc[t], 0, 0, 0);
        }
    }

    #pragma unroll
    for (int t = 0; t < 4; t++) {
        int c = bn * 64 + t * 16 + l16;
        float bb = rdIn(bv, c, f32);
        #pragma unroll
        for (int i = 0; i < 4; i++) {
            int r = bm * 64 + wv * 16 + quad * 4 + i;
            H[(long)r * Nd + c] = f2bs(tanhf(acc[t][i] + bb));
        }
    }
}

// ===========================================================================
// MFMA stage-B: Y = act(H @ W + b) * gate. H = bf16 ws; WT transposed bf16.
// OUTBF: bf16 ws output (X1) vs fp32 final output (d_out is fp32!).
// ===========================================================================
template <bool TANH, bool OUTBF, int SMPSHIFT>
__global__ void fpno_mf_b(const unsigned short* __restrict__ Hs,
                          const unsigned short* __restrict__ WT,
                          const void* __restrict__ bv,
                          const float* __restrict__ gate, const int* __restrict__ flagp,
                          void* __restrict__ Y, int Kd, int Nd) {
    __shared__ unsigned short As[64 * 40];
    const int f32 = *flagp;
    const int tid = threadIdx.x;
    const int lane = tid & 63, wv = tid >> 6;
    const int l16 = lane & 15, quad = lane >> 4;
    const int bm = blockIdx.x, bn = blockIdx.y;
    const int row = tid >> 2, seg = tid & 3;

    v4f acc[4];
    #pragma unroll
    for (int t = 0; t < 4; t++) acc[t] = (v4f){0.f, 0.f, 0.f, 0.f};

    for (int k0 = 0; k0 < Kd; k0 += 32) {
        uint4 hv = *(const uint4*)&Hs[(long)(bm * 64 + row) * Kd + k0 + seg * 8];
        __syncthreads();
        *(uint4*)&As[row * 40 + seg * 8] = hv;
        __syncthreads();

        const v8s a = *(const v8s*)&As[(wv * 16 + l16) * 40 + quad * 8];
        long kg = (long)(k0 + quad * 8);
        #pragma unroll
        for (int t = 0; t < 4; t++) {
            int colg = bn * 64 + t * 16 + l16;
            const v8s b = *(const v8s*)&WT[(long)colg * Kd + kg];
            acc[t] = __builtin_amdgcn_mfma_f32_16x16x32_bf16(a, b, acc[t], 0, 0, 0);
        }
    }

    #pragma unroll
    for (int t = 0; t < 4; t++) {
        int c = bn * 64 + t * 16 + l16;
        float bb = rdIn(bv, c, f32);
        #pragma unroll
        for (int i = 0; i < 4; i++) {
            int r = bm * 64 + wv * 16 + quad * 4 + i;
            float v = acc[t][i] + bb;
            if (TANH) v = tanhf(v);
            v *= gate[(r >> SMPSHIFT) * Nd + c];
            if (OUTBF) ((unsigned short*)Y)[(long)r * Nd + c] = f2bs(v);
            else       ((float*)Y)[(long)r * Nd + c] = v;
        }
    }
}

// ===========================================================================
// output tail (fp32): [pos_skip_l0 (32768*3) | batch_skip_l0 (32768)]
// ===========================================================================
__global__ void fpno_tail(const void* __restrict__ pos0, const int* __restrict__ bt0,
                          const int* __restrict__ flagp, float* __restrict__ out) {
    const int f32 = *flagp;
    int id = blockIdx.x * 256 + threadIdx.x;  // 0..131071
    const int nX = kB * kN0 * kC0;   // 2097152
    const int nP = kB * kN0 * 3;     // 98304
    if (id < nP) out[nX + id] = rdIn(pos0, id, f32);
    else         out[nX + id] = (float)bt0[id - nP];
}

__global__ void fpno_guard(float code, float* __restrict__ out) {
    if (threadIdx.x == 0) out[0] = code;
}

// ===========================================================================
extern "C" void kernel_launch(void* const* d_in, const int* in_sizes, int n_in,
                              void* d_out, int out_size, void* d_ws, size_t ws_size,
                              hipStream_t stream) {
    (void)out_size;
    float* out = (float*)d_out;   // fp32 output buffer
    const int R1 = kB * kN1;  // 8192
    const int R0 = kB * kN0;  // 32768

    static const int kExp[22] = {
        256, 524288, 6144, 2048, 1048576, 24576, 8192, 2097152, 98304, 32768,
        98304, 256, 32768, 128, 8192, 128, 24576, 128, 8192, 64, 4096, 64};
    if (n_in != 22) { fpno_guard<<<1, 64, 0, stream>>>(3072.0f, out); return; }
    for (int i = 0; i < 22; i++) {
        if (in_sizes[i] != kExp[i]) {
            fpno_guard<<<1, 64, 0, stream>>>(1024.0f + 8.0f * i, out);
            return;
        }
    }

    // ---- workspace (~14.3 MB) ----
    char* base = (char*)d_ws;
    size_t off = 0;
    auto alloc = [&](size_t bytes) {
        off = (off + 255) & ~(size_t)255; size_t o = off; off += bytes; return o;
    };
    int*            flag = (int*)(base + alloc(4));
    float*          g0   = (float*)(base + alloc(kB * 128 * 4));
    float*          g1   = (float*)(base + alloc(kB * 64 * 4));
    int*            i1d  = (int*)(base + alloc((size_t)R1 * 3 * 4));
    float*          w1d  = (float*)(base + alloc((size_t)R1 * 3 * 4));
    int*            i0d  = (int*)(base + alloc((size_t)R0 * 3 * 4));
    float*          w0d  = (float*)(base + alloc((size_t)R0 * 3 * 4));
    unsigned short* WT   = (unsigned short*)(base + alloc(163840 * 2));            // 320 KB
    unsigned short* H1   = (unsigned short*)(base + alloc((size_t)R1 * 256 * 2));  // 4 MB
    unsigned short* X1   = (unsigned short*)(base + alloc((size_t)R1 * 128 * 2));  // 2 MB
    unsigned short* H2   = (unsigned short*)(base + alloc((size_t)R0 * 128 * 2));  // 8 MB
    if (ws_size < off) { fpno_guard<<<1, 64, 0, stream>>>(2048.0f, out); return; }
    unsigned short* WT0a = WT;            // 256 x 384
    unsigned short* WT0b = WT + 98304;    // 128 x 256
    unsigned short* WT1a = WT + 131072;   // 128 x 192
    unsigned short* WT1b = WT + 155648;   // 64 x 128

    const void* par  = d_in[0];
    const void* x    = d_in[1];
    const void* pos  = d_in[2];
    const void* xs1  = d_in[4];
    const void* pos1 = d_in[5];
    const void* xs0  = d_in[7];
    const void* pos0 = d_in[8];
    const int*  bt0  = (const int*)d_in[9];
    const void *W0a = d_in[10], *b0a = d_in[11], *W0b = d_in[12], *b0b = d_in[13];
    const void *Wp0 = d_in[14], *bp0 = d_in[15];
    const void *W1a = d_in[16], *b1a = d_in[17], *W1b = d_in[18], *b1b = d_in[19];
    const void *Wp1 = d_in[20], *bp1 = d_in[21];

    // 1) input dtype probe
    fpno_probe_dtype<<<1, 256, 0, stream>>>((const unsigned int*)pos, flag);

    // 2) weight transpose/convert (one-time, 320 KB, L2-resident thereafter)
    fpno_wconv<<<640, 256, 0, stream>>>(W0a, W0b, W1a, W1b, flag, WT);

    // 3) per-sample gates
    fpno_gates<<<3, 256, 0, stream>>>(par, Wp0, bp0, Wp1, bp1, flag, g0, g1);

    // 4) layer-1 kNN
    fpno_nn3s<kN2><<<R1 / 32, 256, 0, stream>>>(pos, pos1, flag, kN1, i1d, w1d);

    // 5) H1 = tanh([interp(x), xs1] @ W0a + b0a)    8192x384 @ 384x256  (MFMA)
    fpno_mf_a<kC2, kC1><<<dim3(R1 / 64, 4), 256, 0, stream>>>(
        x, nullptr, xs1, WT0a, b0a, i1d, w1d, flag, H1, 256);

    // 6) X1 = tanh(H1 @ W0b + b0b) * g0             8192x256 @ 256x128  (MFMA)
    fpno_mf_b<true, true, 11><<<dim3(R1 / 64, 2), 256, 0, stream>>>(
        H1, WT0b, b0b, g0, flag, X1, 256, 128);

    // 7) layer-2 kNN
    fpno_nn3s<kN1><<<R0 / 32, 256, 0, stream>>>(pos1, pos0, flag, kN0, i0d, w0d);

    // 8) H2 = tanh([interp(X1), xs0] @ W1a + b1a)   32768x192 @ 192x128 (MFMA)
    fpno_mf_a<kC1, kC0><<<dim3(R0 / 64, 2), 256, 0, stream>>>(
        nullptr, X1, xs0, WT1a, b1a, i0d, w0d, flag, H2, 128);

    // 9) x0 = (H2 @ W1b + b1b) * g1 -> fp32 out     32768x128 @ 128x64  (MFMA)
    fpno_mf_b<false, false, 13><<<dim3(R0 / 64, 1), 256, 0, stream>>>(
        H2, WT1b, b1b, g1, flag, out, 128, 64);

    // 10) tail passthrough (fp32)
    fpno_tail<<<(kB * kN0 * 4) / 256, 256, 0, stream>>>(pos0, bt0, flag, out);
}